// Round 6
// baseline (586.923 us; speedup 1.0000x reference)
//
#include <hip/hip_runtime.h>
#include <math.h>

// KGATConv: N=50000, E=800000, D=64, R=16, fp32.
// R12: k_attE micro-fix (R11 structure kept, its three taxes removed):
//   - W_r pre-transposed ONCE into fragment-ready f16 WT[r][col][k] (128KB,
//     L2-resident; done by k_histT blocks 0..15). k_attE loads B-fragments
//     directly from global -> shB transpose-scatter (8-way LDS conflict,
//     13.6M conflict cycles) eliminated.
//   - shS/shD staging vectorized to half4 8B stores (2-way = free).
//   - efeat staged through LDS (coalesced float4 bursts overlaying shS/shD
//     after fragment loads; issues before MFMA -> latency hidden) instead of
//     16 scalar global loads/thread in the dot phase.
//   - launch merges: k_hist+k_thist -> k_histT; k_scan2+k_tscan -> k_scanF.

#define DIM 64
#define PA 72

typedef _Float16 half8 __attribute__((ext_vector_type(8)));
typedef _Float16 half4 __attribute__((ext_vector_type(4)));
typedef float f32x4 __attribute__((ext_vector_type(4)));

__device__ __forceinline__ float4 f4zero() { return make_float4(0.f, 0.f, 0.f, 0.f); }

__device__ __forceinline__ float fast_tanh(float x) {
    float ex = __expf(2.0f * x);
    return 1.0f - 2.0f / (ex + 1.0f);
}

// ---------------------------------------------------------------------------
// Fused: dst-CSR rank/deg + etype block-histogram + (blocks 0..15) relW
// transpose into fragment-ready f16 WT[r][col][k].
// ---------------------------------------------------------------------------
__global__ __launch_bounds__(256) void k_histT(const int* __restrict__ dst,
                                               const int* __restrict__ etype,
                                               const float* __restrict__ relW,
                                               int* __restrict__ deg,
                                               int* __restrict__ rank,
                                               int* __restrict__ bh,
                                               _Float16* __restrict__ WT,
                                               int nbe, int E) {
    __shared__ int h[16];
    const int tx = threadIdx.x, b = blockIdx.x;
    if (tx < 16) h[tx] = 0;
    __syncthreads();
    int e = b * 256 + tx;
    if (e < E) {
        rank[e] = atomicAdd(&deg[dst[e]], 1);
        atomicAdd(&h[etype[e]], 1);
    }
    __syncthreads();
    if (tx < 16) bh[(size_t)tx * nbe + b] = h[tx];

    if (b < 16) {   // one-time W transpose, r = b
        const float4* Wr4 = (const float4*)(relW + (size_t)b * DIM * DIM);
        _Float16* wt = WT + (size_t)b * DIM * DIM;
#pragma unroll
        for (int i = 0; i < 4; ++i) {
            int idx = tx + 256 * i;
            int k = idx >> 4, c4 = (idx & 15) * 4;
            float4 v = Wr4[idx];
            wt[(c4 + 0) * DIM + k] = (_Float16)v.x;
            wt[(c4 + 1) * DIM + k] = (_Float16)v.y;
            wt[(c4 + 2) * DIM + k] = (_Float16)v.z;
            wt[(c4 + 3) * DIM + k] = (_Float16)v.w;
        }
    }
}

__global__ __launch_bounds__(256) void k_scan1(const int* __restrict__ deg,
                                               int* __restrict__ epart,
                                               int* __restrict__ bsum, int N) {
    __shared__ int sh[256];
    int i = blockIdx.x * 256 + threadIdx.x;
    int t = threadIdx.x;
    int v = (i < N) ? deg[i] : 0;
    sh[t] = v;
    __syncthreads();
#pragma unroll
    for (int d = 1; d < 256; d <<= 1) {
        int o = (t >= d) ? sh[t - d] : 0;
        __syncthreads();
        sh[t] += o;
        __syncthreads();
    }
    if (i < N) epart[i] = sh[t] - v;
    if (t == 255) bsum[blockIdx.x] = sh[255];
}

// ---------------------------------------------------------------------------
// Merged: per-type block-count scan (-> bh absolute bases + hdr) AND the
// node-offset finalization (bsum scan -> off). One block, 1024 threads.
// ---------------------------------------------------------------------------
__global__ __launch_bounds__(1024) void k_scanF(int* __restrict__ bh, int nbe,
                                                int* __restrict__ hdr,
                                                const int* __restrict__ epart,
                                                const int* __restrict__ bsum,
                                                int nb,
                                                int* __restrict__ off,
                                                int N, int E) {
    __shared__ int cntS[16];
    __shared__ int tstartS[16];
    __shared__ int bx[256];
    const int tx = threadIdx.x;
    const int w = tx >> 6;        // 0..15
    const int lane = tx & 63;

    // phase A: scan type w's block counts
    {
        int* row = bh + (size_t)w * nbe;
        int run = 0;
        for (int i0 = 0; i0 < nbe; i0 += 64) {
            int idx = i0 + lane;
            int v = (idx < nbe) ? row[idx] : 0;
            int incl = v;
#pragma unroll
            for (int d = 1; d < 64; d <<= 1) {
                int o = __shfl_up(incl, d);
                if (lane >= d) incl += o;
            }
            if (idx < nbe) row[idx] = run + (incl - v);
            run += __shfl(incl, 63);
        }
        if (lane == 0) cntS[w] = run;
    }
    __syncthreads();
    if (tx == 0) {
        int ts = 0, tp = 0;
        for (int r = 0; r < 16; ++r) {
            tstartS[r] = ts;
            hdr[r] = ts;
            hdr[17 + r] = tp;
            ts += cntS[r];
            tp += (cntS[r] + 63) >> 6;
        }
        hdr[16] = ts;
        hdr[33] = tp;
    }
    __syncthreads();
    {
        const int t0 = tstartS[w];
        int* row = bh + (size_t)w * nbe;
        for (int i0 = 0; i0 < nbe; i0 += 64) {
            int idx = i0 + lane;
            if (idx < nbe) row[idx] += t0;
        }
    }
    // phase B: node offsets
    int v = 0;
    if (tx < 256) {
        v = (tx < nb) ? bsum[tx] : 0;
        bx[tx] = v;
    }
    __syncthreads();
#pragma unroll
    for (int d = 1; d < 256; d <<= 1) {
        int o = 0;
        if (tx < 256 && tx >= d) o = bx[tx - d];
        __syncthreads();
        if (tx < 256) bx[tx] += o;
        __syncthreads();
    }
    if (tx < 256) bx[tx] -= v;
    __syncthreads();
    for (int i = tx; i < N; i += 1024)
        off[i] = epart[i] + bx[i >> 8];
    if (tx == 0) off[N] = E;
}

__global__ __launch_bounds__(256) void k_tfill(const int* __restrict__ src,
                                               const int* __restrict__ dst,
                                               const int* __restrict__ etype,
                                               const int* __restrict__ rank,
                                               const int* __restrict__ off,
                                               const int* __restrict__ bh, int nbe,
                                               int* __restrict__ sS,
                                               int* __restrict__ dS,
                                               int* __restrict__ pS,
                                               int* __restrict__ eS, int E) {
    __shared__ int h[16];
    const int tx = threadIdx.x, b = blockIdx.x;
    if (tx < 16) h[tx] = 0;
    __syncthreads();
    int e = b * 256 + tx;
    if (e < E) {
        int r = etype[e];
        int mr = atomicAdd(&h[r], 1);
        int slot = bh[(size_t)r * nbe + b] + mr;
        int d = dst[e];
        sS[slot] = src[e];
        dS[slot] = d;
        pS[slot] = off[d] + rank[e];
        eS[slot] = e;
    }
}

// ---------------------------------------------------------------------------
// Fused attention: 64 same-type edges per block.
// B-fragments straight from global WT (no LDS transpose); src/dst tiles
// staged as half4 (conflict-free); efeat staged through LDS overlay.
// ---------------------------------------------------------------------------
__global__ __launch_bounds__(256) void k_attE(const float* __restrict__ nfeat,
                                              const float* __restrict__ efeat,
                                              const _Float16* __restrict__ WT,
                                              const int* __restrict__ hdr,
                                              const int* __restrict__ sS,
                                              const int* __restrict__ dS,
                                              const int* __restrict__ pS,
                                              const int* __restrict__ eS,
                                              float* __restrict__ att_s,
                                              int* __restrict__ src_s) {
    __shared__ _Float16 shMem[2 * 64 * PA];   // 18432 B
    _Float16* shS = shMem;
    _Float16* shD = shMem + 64 * PA;

    const int bid = blockIdx.x;
    if (bid >= hdr[33]) return;
    int r = 0;
    while (r < 15 && bid >= hdr[17 + r + 1]) ++r;
    const int e0 = hdr[r] + ((bid - hdr[17 + r]) << 6);
    const int cnt = min(64, hdr[r + 1] - e0);
    const int tx = threadIdx.x;

    // gather src/dst nfeat rows -> f16 tiles (half4 8B stores, 2-way banks)
#pragma unroll
    for (int i = 0; i < 4; ++i) {
        int idx = tx + 256 * i;
        int row = idx >> 4, c = idx & 15;
        bool ok = (row < cnt);
        int sn = ok ? sS[e0 + row] : 0;
        int dn = ok ? dS[e0 + row] : 0;
        float4 a = ok ? *(const float4*)&nfeat[(size_t)sn * DIM + c * 4] : f4zero();
        float4 b = ok ? *(const float4*)&nfeat[(size_t)dn * DIM + c * 4] : f4zero();
        half4 ha = {(_Float16)a.x, (_Float16)a.y, (_Float16)a.z, (_Float16)a.w};
        half4 hb = {(_Float16)b.x, (_Float16)b.y, (_Float16)b.z, (_Float16)b.w};
        *(half4*)&shS[row * PA + c * 4] = ha;
        *(half4*)&shD[row * PA + c * 4] = hb;
    }
    __syncthreads();

    const int w = tx >> 6;
    const int lane = tx & 63;
    const int lm = lane & 15;
    const int lq = lane >> 4;
    const int m0 = w * 16;

    half8 as0 = *(const half8*)&shS[(m0 + lm) * PA + lq * 8];
    half8 as1 = *(const half8*)&shS[(m0 + lm) * PA + 32 + lq * 8];
    half8 ad0 = *(const half8*)&shD[(m0 + lm) * PA + lq * 8];
    half8 ad1 = *(const half8*)&shD[(m0 + lm) * PA + 32 + lq * 8];

    // B fragments direct from global WT (128KB table, L2-resident)
    const _Float16* wt = WT + (size_t)r * DIM * DIM;
    half8 b0[4], b1[4];
#pragma unroll
    for (int ct = 0; ct < 4; ++ct) {
        b0[ct] = *(const half8*)&wt[(ct * 16 + lm) * DIM + lq * 8];
        b1[ct] = *(const half8*)&wt[(ct * 16 + lm) * DIM + 32 + lq * 8];
    }
    __syncthreads();   // all shS/shD fragment reads done -> overlay allowed

    // stage efeat rows (coalesced float4, nt) into the overlay buffer;
    // these global loads issue now and complete under the MFMAs below.
    float* shE = (float*)shMem;   // 64*68*4 = 17408 B <= 18432 B
#pragma unroll
    for (int i = 0; i < 4; ++i) {
        int idx = tx + 256 * i;
        int row = idx >> 4, c = idx & 15;
        if (row < cnt) {
            int e = eS[e0 + row];
            f32x4 v = __builtin_nontemporal_load(
                (const f32x4*)&efeat[(size_t)e * DIM + c * 4]);
            *(f32x4*)&shE[row * 68 + c * 4] = v;
        }
    }

    f32x4 T[4], H[4];
#pragma unroll
    for (int ct = 0; ct < 4; ++ct) {
        f32x4 c1 = {0.f, 0.f, 0.f, 0.f};
        f32x4 c2 = {0.f, 0.f, 0.f, 0.f};
        c1 = __builtin_amdgcn_mfma_f32_16x16x32_f16(as0, b0[ct], c1, 0, 0, 0);
        c1 = __builtin_amdgcn_mfma_f32_16x16x32_f16(as1, b1[ct], c1, 0, 0, 0);
        c2 = __builtin_amdgcn_mfma_f32_16x16x32_f16(ad0, b0[ct], c2, 0, 0, 0);
        c2 = __builtin_amdgcn_mfma_f32_16x16x32_f16(ad1, b1[ct], c2, 0, 0, 0);
        T[ct] = c1;
        H[ct] = c2;
    }
    __syncthreads();   // shE ready

    float part[4] = {0.f, 0.f, 0.f, 0.f};
#pragma unroll
    for (int ct = 0; ct < 4; ++ct) {
        int col = ct * 16 + lm;
#pragma unroll
        for (int i = 0; i < 4; ++i) {
            int row = m0 + lq * 4 + i;
            float ef = shE[row * 68 + col];
            part[i] = fmaf(T[ct][i], fast_tanh(H[ct][i] + ef), part[i]);
        }
    }
#pragma unroll
    for (int i = 0; i < 4; ++i) {
        part[i] += __shfl_xor(part[i], 1);
        part[i] += __shfl_xor(part[i], 2);
        part[i] += __shfl_xor(part[i], 4);
        part[i] += __shfl_xor(part[i], 8);
    }
    if (lm == 0) {
#pragma unroll
        for (int i = 0; i < 4; ++i) {
            int row = m0 + lq * 4 + i;
            if (row < cnt) {
                int p = pS[e0 + row];
                att_s[p] = part[i];
                src_s[p] = sS[e0 + row];
            }
        }
    }
}

// ---------------------------------------------------------------------------
// Pure softmax + aggregation. Wave per node, NO LDS.
// Quarter-wave float4 gathers: one VMEM instr covers 4 nfeat rows.
// ---------------------------------------------------------------------------
__global__ __launch_bounds__(256) void k_agg(const float* __restrict__ att_s,
                                             const int* __restrict__ src_s,
                                             const float* __restrict__ nfeat,
                                             const int* __restrict__ off,
                                             float* __restrict__ hn, int N) {
    const int node = blockIdx.x * 4 + (threadIdx.x >> 6);
    if (node >= N) return;
    const int lane = threadIdx.x & 63;
    const int qw = lane >> 4;
    const int ql = lane & 15;

    const int jb = off[node];
    const int je = off[node + 1];

    float m = -INFINITY;
    for (int j0 = jb; j0 < je; j0 += 64) {
        int j = j0 + lane;
        float a = (j < je) ? att_s[j] : -INFINITY;
        m = fmaxf(m, a);
    }
#pragma unroll
    for (int ms = 32; ms; ms >>= 1) m = fmaxf(m, __shfl_xor(m, ms));

    float pl = 0.f;
    f32x4 acc = {0.f, 0.f, 0.f, 0.f};
    for (int j0 = jb; j0 < je; j0 += 64) {
        int j = j0 + lane;
        int cnt = min(64, je - j0);
        float a = (j < je) ? att_s[j] : -INFINITY;
        float p = __expf(a - m);
        int s = (j < je) ? src_s[j] : 0;
        pl += p;

        int jj = 0;
        for (; jj + 15 < cnt; jj += 16) {
            float pj[4]; int sj[4]; f32x4 x[4];
#pragma unroll
            for (int u = 0; u < 4; ++u) {
                int eidx = jj + u * 4 + qw;
                pj[u] = __shfl(p, eidx);
                sj[u] = __shfl(s, eidx);
            }
#pragma unroll
            for (int u = 0; u < 4; ++u)
                x[u] = *(const f32x4*)&nfeat[(size_t)sj[u] * DIM + ql * 4];
#pragma unroll
            for (int u = 0; u < 4; ++u) {
                acc[0] = fmaf(pj[u], x[u][0], acc[0]);
                acc[1] = fmaf(pj[u], x[u][1], acc[1]);
                acc[2] = fmaf(pj[u], x[u][2], acc[2]);
                acc[3] = fmaf(pj[u], x[u][3], acc[3]);
            }
        }
        for (; jj < cnt; jj += 4) {
            int eidx = jj + qw;
            int ec = (eidx < cnt) ? eidx : (cnt - 1);
            float pj = __shfl(p, ec);
            int sj = __shfl(s, ec);
            if (eidx < cnt) {
                f32x4 x = *(const f32x4*)&nfeat[(size_t)sj * DIM + ql * 4];
                acc[0] = fmaf(pj, x[0], acc[0]);
                acc[1] = fmaf(pj, x[1], acc[1]);
                acc[2] = fmaf(pj, x[2], acc[2]);
                acc[3] = fmaf(pj, x[3], acc[3]);
            }
        }
    }
#pragma unroll
    for (int ms = 32; ms; ms >>= 1) pl += __shfl_xor(pl, ms);

#pragma unroll
    for (int c = 0; c < 4; ++c) {
        acc[c] += __shfl_xor(acc[c], 16);
        acc[c] += __shfl_xor(acc[c], 32);
    }

    const float inv = (je > jb) ? 1.0f / pl : 0.f;
    if (qw == 0) {
        f32x4 hv = {acc[0] * inv, acc[1] * inv, acc[2] * inv, acc[3] * inv};
        *(f32x4*)&hn[(size_t)node * DIM + ql * 4] = hv;
    }
}

// ---------------------------------------------------------------------------
// Bi-interaction: out = lrelu((nf+hn)@W1) + lrelu((nf*hn)@W2), MFMA f16.
// ---------------------------------------------------------------------------
__global__ __launch_bounds__(256) void k_bi(const float* __restrict__ nfeat,
                                            const float* __restrict__ hn,
                                            const float* __restrict__ W1,
                                            const float* __restrict__ W2,
                                            float* __restrict__ out, int N) {
    __shared__ _Float16 shMem[4 * 64 * PA];
    _Float16* shA1 = shMem;
    _Float16* shA2 = shMem + 64 * PA;
    _Float16* shB1 = shMem + 2 * 64 * PA;
    _Float16* shB2 = shMem + 3 * 64 * PA;

    const int tx = threadIdx.x;
    const int n0 = blockIdx.x * 64;

    const float4* nf4 = (const float4*)(nfeat + (size_t)n0 * DIM);
    const float4* hn4 = (const float4*)(hn + (size_t)n0 * DIM);
#pragma unroll
    for (int i = 0; i < 4; ++i) {
        int idx = tx + 256 * i;
        int row = idx >> 4, c = idx & 15;
        bool ok = (n0 + row < N);
        float4 a = ok ? nf4[idx] : f4zero();
        float4 b = ok ? hn4[idx] : f4zero();
        _Float16* p1 = &shA1[row * PA + c * 4];
        _Float16* p2 = &shA2[row * PA + c * 4];
        p1[0] = (_Float16)(a.x + b.x); p2[0] = (_Float16)(a.x * b.x);
        p1[1] = (_Float16)(a.y + b.y); p2[1] = (_Float16)(a.y * b.y);
        p1[2] = (_Float16)(a.z + b.z); p2[2] = (_Float16)(a.z * b.z);
        p1[3] = (_Float16)(a.w + b.w); p2[3] = (_Float16)(a.w * b.w);
    }
    const float4* w14 = (const float4*)W1;
    const float4* w24 = (const float4*)W2;
#pragma unroll
    for (int i = 0; i < 4; ++i) {
        int idx = tx + 256 * i;
        int k = idx >> 4, c = (idx & 15) * 4;
        float4 v = w14[idx];
        shB1[(c + 0) * PA + k] = (_Float16)v.x;
        shB1[(c + 1) * PA + k] = (_Float16)v.y;
        shB1[(c + 2) * PA + k] = (_Float16)v.z;
        shB1[(c + 3) * PA + k] = (_Float16)v.w;
        float4 u = w24[idx];
        shB2[(c + 0) * PA + k] = (_Float16)u.x;
        shB2[(c + 1) * PA + k] = (_Float16)u.y;
        shB2[(c + 2) * PA + k] = (_Float16)u.z;
        shB2[(c + 3) * PA + k] = (_Float16)u.w;
    }
    __syncthreads();

    const int w = tx >> 6;
    const int lane = tx & 63;
    const int lm = lane & 15;
    const int lq = lane >> 4;
    const int m0 = w * 16;

    half8 a10 = *(const half8*)&shA1[(m0 + lm) * PA + lq * 8];
    half8 a11 = *(const half8*)&shA1[(m0 + lm) * PA + 32 + lq * 8];
    half8 a20 = *(const half8*)&shA2[(m0 + lm) * PA + lq * 8];
    half8 a21 = *(const half8*)&shA2[(m0 + lm) * PA + 32 + lq * 8];

    f32x4 res[4];
#pragma unroll
    for (int ct = 0; ct < 4; ++ct) {
        half8 b10 = *(const half8*)&shB1[(ct * 16 + lm) * PA + lq * 8];
        half8 b11 = *(const half8*)&shB1[(ct * 16 + lm) * PA + 32 + lq * 8];
        half8 b20 = *(const half8*)&shB2[(ct * 16 + lm) * PA + lq * 8];
        half8 b21 = *(const half8*)&shB2[(ct * 16 + lm) * PA + 32 + lq * 8];
        f32x4 c1 = {0.f, 0.f, 0.f, 0.f};
        f32x4 c2 = {0.f, 0.f, 0.f, 0.f};
        c1 = __builtin_amdgcn_mfma_f32_16x16x32_f16(a10, b10, c1, 0, 0, 0);
        c1 = __builtin_amdgcn_mfma_f32_16x16x32_f16(a11, b11, c1, 0, 0, 0);
        c2 = __builtin_amdgcn_mfma_f32_16x16x32_f16(a20, b20, c2, 0, 0, 0);
        c2 = __builtin_amdgcn_mfma_f32_16x16x32_f16(a21, b21, c2, 0, 0, 0);
#pragma unroll
        for (int i = 0; i < 4; ++i) {
            float o1 = c1[i], o2 = c2[i];
            res[ct][i] = (o1 >= 0.f ? o1 : 0.01f * o1) + (o2 >= 0.f ? o2 : 0.01f * o2);
        }
    }

    __syncthreads();
    float* shSt = (float*)shMem;   // 64*68*4 = 17408B <= 36864B
#pragma unroll
    for (int ct = 0; ct < 4; ++ct)
#pragma unroll
        for (int i = 0; i < 4; ++i)
            shSt[(m0 + lq * 4 + i) * 68 + ct * 16 + lm] = res[ct][i];
    __syncthreads();

    float* outp = out + (size_t)n0 * DIM;
#pragma unroll
    for (int k = 0; k < 4; ++k) {
        int idx = tx + 256 * k;
        int row = idx >> 4, cc = idx & 15;
        if (n0 + row < N) {
            float4 v = *(const float4*)&shSt[row * 68 + cc * 4];
            *(float4*)&outp[(size_t)row * DIM + cc * 4] = v;
        }
    }
}

extern "C" void kernel_launch(void* const* d_in, const int* in_sizes, int n_in,
                              void* d_out, int out_size, void* d_ws, size_t ws_size,
                              hipStream_t stream) {
    const float* nfeat = (const float*)d_in[0];
    const float* efeat = (const float*)d_in[1];
    const float* relW  = (const float*)d_in[2];
    const float* W1    = (const float*)d_in[3];
    const float* W2    = (const float*)d_in[4];
    const int* src   = (const int*)d_in[5];
    const int* dst   = (const int*)d_in[6];
    const int* etype = (const int*)d_in[7];

    const int N = in_sizes[0] / DIM;
    const int E = in_sizes[5];
    const int NB = (N + 255) / 256;    // dst-scan blocks (<=256)
    const int NBE = (E + 255) / 256;   // edge blocks

    float* out = (float*)d_out;
    float* hn  = out;
    float* bi  = out + (size_t)N * DIM;

    // ws: deg[N] | off[N+1] | epart[N] | bsum[256] | rank[E] | src_s[E] |
    //     att_s[E] | bh[16*NBE] | hdr[64] | sS[E] | dS[E] | pS[E] | eS[E] | WT
    int* deg    = (int*)d_ws;
    int* off    = deg + N;
    int* epart  = off + (N + 1);
    int* bsum   = epart + N;
    int* rank   = bsum + 256;
    int* src_s  = rank + E;
    float* att_s = (float*)(src_s + E);
    int* bh     = (int*)(att_s + E);
    int* hdr    = bh + (size_t)16 * NBE;
    int* sS     = hdr + 64;
    int* dS     = sS + E;
    int* pS     = dS + E;
    int* eS     = pS + E;
    _Float16* WT = (_Float16*)(eS + E);

    (void)hipMemsetAsync(deg, 0, (size_t)N * sizeof(int), stream);

    k_histT<<<NBE, 256, 0, stream>>>(dst, etype, relW, deg, rank, bh, WT, NBE, E);
    k_scan1<<<NB, 256, 0, stream>>>(deg, epart, bsum, N);
    k_scanF<<<1, 1024, 0, stream>>>(bh, NBE, hdr, epart, bsum, NB, off, N, E);
    k_tfill<<<NBE, 256, 0, stream>>>(src, dst, etype, rank, off, bh, NBE,
                                     sS, dS, pS, eS, E);

    const int nTiles = (E + 63) / 64 + 16;
    k_attE<<<nTiles, 256, 0, stream>>>(nfeat, efeat, WT, hdr,
                                       sS, dS, pS, eS, att_s, src_s);

    k_agg<<<(N + 3) / 4, 256, 0, stream>>>(att_s, src_s, nfeat, off, hn, N);

    k_bi<<<(N + 63) / 64, 256, 0, stream>>>(nfeat, hn, W1, W2, bi, N);
}

// Round 7
// 486.012 us; speedup vs baseline: 1.2076x; 1.2076x over previous
//
#include <hip/hip_runtime.h>
#include <math.h>

// KGATConv: N=50000, E=800000, D=64, R=16, fp32.
// R13 = R10 base (best, 468.7us) + ONE change: k_att processes 2 edges per
// 8-lane group (8 proj gathers + 4 efeat streams in flight per thread,
// 2x memory-level parallelism). R11/R12's fused-attention arc reverted:
// its LDS-staged efeat serialized HBM latency ahead of the MFMAs
// (counter evidence: BW 1.6TB/s, conflicts fixed but slower).

#define DIM 64
#define PA 72

typedef _Float16 half8 __attribute__((ext_vector_type(8)));
typedef float f32x4 __attribute__((ext_vector_type(4)));
typedef unsigned int u32x4 __attribute__((ext_vector_type(4)));

__device__ __forceinline__ float4 f4zero() { return make_float4(0.f, 0.f, 0.f, 0.f); }

__device__ __forceinline__ unsigned short f2bf(float x) {
    unsigned u = __float_as_uint(x);
    u += 0x7FFFu + ((u >> 16) & 1u);   // RNE
    return (unsigned short)(u >> 16);
}

__device__ __forceinline__ float fast_tanh(float x) {
    float ex = __expf(2.0f * x);
    return 1.0f - 2.0f / (ex + 1.0f);
}

// unpack 8 bf16 (in a u32x4) to fp32
__device__ __forceinline__ void bf8up(u32x4 u, float* f) {
    f[0] = __uint_as_float(u[0] << 16);
    f[1] = __uint_as_float(u[0] & 0xFFFF0000u);
    f[2] = __uint_as_float(u[1] << 16);
    f[3] = __uint_as_float(u[1] & 0xFFFF0000u);
    f[4] = __uint_as_float(u[2] << 16);
    f[5] = __uint_as_float(u[2] & 0xFFFF0000u);
    f[6] = __uint_as_float(u[3] << 16);
    f[7] = __uint_as_float(u[3] & 0xFFFF0000u);
}

// ---------------------------------------------------------------------------
// proj[r,n,:] = bf16( nfeat[n,:] @ relW[r,:,:] ) via mfma_f32_16x16x32_f16
// A-tile + fragments loaded once; each block loops over R/4 relations.
// Output bounced through LDS -> coalesced 16B stores.
// ---------------------------------------------------------------------------
__global__ __launch_bounds__(256) void k_proj(const float* __restrict__ nfeat,
                                              const float* __restrict__ relW,
                                              unsigned short* __restrict__ proj,
                                              int N, int R) {
    __shared__ _Float16 shA[64 * PA];
    __shared__ _Float16 shB[64 * PA];
    unsigned short* shSt = (unsigned short*)shA;   // store-staging (shA dead after frag load)

    const int tx = threadIdx.x;
    const int n0 = blockIdx.x * 64;
    const int rpb = R >> 2;                 // relations per block (grid.y == 4)
    const int rb = blockIdx.y * rpb;

    const float4* nf4 = (const float4*)(nfeat + (size_t)n0 * DIM);
#pragma unroll
    for (int i = 0; i < 4; ++i) {
        int idx = tx + 256 * i;
        int row = idx >> 4, c = idx & 15;
        float4 v = (n0 + row < N) ? nf4[idx] : f4zero();
        _Float16* p = &shA[row * PA + c * 4];
        p[0] = (_Float16)v.x; p[1] = (_Float16)v.y;
        p[2] = (_Float16)v.z; p[3] = (_Float16)v.w;
    }
    __syncthreads();

    const int w = tx >> 6;
    const int lane = tx & 63;
    const int lm = lane & 15;
    const int lq = lane >> 4;
    const int m0 = w * 16;

    // A fragments are relation-independent: load once.
    half8 a0 = *(const half8*)&shA[(m0 + lm) * PA + 0 * 32 + lq * 8];
    half8 a1 = *(const half8*)&shA[(m0 + lm) * PA + 1 * 32 + lq * 8];

    for (int rr = 0; rr < rpb; ++rr) {
        const int r = rb + rr;
        __syncthreads();   // prev iter's shB mfma-reads + shSt store-reads complete
        const float4* Wr4 = (const float4*)(relW + (size_t)r * DIM * DIM);
#pragma unroll
        for (int i = 0; i < 4; ++i) {
            int idx = tx + 256 * i;
            int d = idx >> 4, c = (idx & 15) * 4;
            float4 v = Wr4[idx];
            shB[(c + 0) * PA + d] = (_Float16)v.x;
            shB[(c + 1) * PA + d] = (_Float16)v.y;
            shB[(c + 2) * PA + d] = (_Float16)v.z;
            shB[(c + 3) * PA + d] = (_Float16)v.w;
        }
        __syncthreads();

        f32x4 acc[4];
#pragma unroll
        for (int ct = 0; ct < 4; ++ct) {
            half8 b0 = *(const half8*)&shB[(ct * 16 + lm) * PA + 0 * 32 + lq * 8];
            half8 b1 = *(const half8*)&shB[(ct * 16 + lm) * PA + 1 * 32 + lq * 8];
            f32x4 c = {0.f, 0.f, 0.f, 0.f};
            c = __builtin_amdgcn_mfma_f32_16x16x32_f16(a0, b0, c, 0, 0, 0);
            c = __builtin_amdgcn_mfma_f32_16x16x32_f16(a1, b1, c, 0, 0, 0);
            acc[ct] = c;
        }

        // stage bf16 result in LDS (row stride 72 ushort -> 144B, 16B aligned)
#pragma unroll
        for (int ct = 0; ct < 4; ++ct) {
#pragma unroll
            for (int i = 0; i < 4; ++i) {
                int row = m0 + lq * 4 + i;
                int col = ct * 16 + lm;
                shSt[row * PA + col] = f2bf(acc[ct][i]);
            }
        }
        __syncthreads();

        // coalesced stores: 512 x 16B chunks, 2 per thread; wave covers 1KB
        unsigned short* projR = proj + ((size_t)r * N + n0) * DIM;
#pragma unroll
        for (int k = 0; k < 2; ++k) {
            int chunk = tx + k * 256;
            int row = chunk >> 3, cc = chunk & 7;
            uint4 v = *(const uint4*)&shSt[row * PA + cc * 8];
            if (n0 + row < N)
                *(uint4*)&projR[(size_t)row * DIM + cc * 8] = v;
        }
    }
}

// ---------------------------------------------------------------------------
// CSR build: k_hist's atomic return value is the within-segment rank.
// ---------------------------------------------------------------------------
__global__ __launch_bounds__(256) void k_hist(const int* __restrict__ dst,
                                              int* __restrict__ deg,
                                              int* __restrict__ rank, int E) {
    int e = blockIdx.x * 256 + threadIdx.x;
    if (e < E) rank[e] = atomicAdd(&deg[dst[e]], 1);
}

__global__ __launch_bounds__(256) void k_scan1(const int* __restrict__ deg,
                                               int* __restrict__ epart,
                                               int* __restrict__ bsum, int N) {
    __shared__ int sh[256];
    int i = blockIdx.x * 256 + threadIdx.x;
    int t = threadIdx.x;
    int v = (i < N) ? deg[i] : 0;
    sh[t] = v;
    __syncthreads();
#pragma unroll
    for (int d = 1; d < 256; d <<= 1) {
        int o = (t >= d) ? sh[t - d] : 0;
        __syncthreads();
        sh[t] += o;
        __syncthreads();
    }
    if (i < N) epart[i] = sh[t] - v;
    if (t == 255) bsum[blockIdx.x] = sh[255];
}

__global__ __launch_bounds__(1024) void k_scan2(const int* __restrict__ epart,
                                                const int* __restrict__ bsum,
                                                int nb,
                                                int* __restrict__ off,
                                                int N, int E) {
    __shared__ int bx[256];
    int t = threadIdx.x;
    int v = 0;
    if (t < 256) {
        v = (t < nb) ? bsum[t] : 0;
        bx[t] = v;
    }
    __syncthreads();
#pragma unroll
    for (int d = 1; d < 256; d <<= 1) {
        int o = 0;
        if (t < 256 && t >= d) o = bx[t - d];
        __syncthreads();
        if (t < 256) bx[t] += o;
        __syncthreads();
    }
    if (t < 256) bx[t] -= v;   // exclusive block prefix
    __syncthreads();
    for (int i = t; i < N; i += 1024)
        off[i] = epart[i] + bx[i >> 8];
    if (t == 0) off[N] = E;
}

// ---------------------------------------------------------------------------
// Attention, 8 threads per TWO edges: each thread holds both edges' 8-dim
// slices -> 8 gathered dwordx4 + 4 streamed dwordx4 in flight (2x MLP of the
// 1-edge version). p = off[dst] + rank (atomic-free CSR slot).
// sub0/1 write edge A's (att,src); sub2/3 write edge B's.
// ---------------------------------------------------------------------------
__global__ __launch_bounds__(256) void k_att(const unsigned short* __restrict__ proj,
                                             const float* __restrict__ efeat,
                                             const int* __restrict__ src,
                                             const int* __restrict__ dst,
                                             const int* __restrict__ etype,
                                             const int* __restrict__ rank,
                                             const int* __restrict__ off,
                                             float* __restrict__ att_s,
                                             int* __restrict__ src_s,
                                             int N, int E) {
    int t = blockIdx.x * 256 + threadIdx.x;
    int g = t >> 3;
    int sub = t & 7;
    int eA = g * 2;
    if (eA >= E) return;
    int eB = eA + 1;
    bool hasB = (eB < E);
    int eBc = hasB ? eB : eA;   // clamped (loads valid, writes gated)

    int sA = src[eA], dA = dst[eA], rA = etype[eA];
    int sB = src[eBc], dB = dst[eBc], rB = etype[eBc];

    const u32x4* tpA = (const u32x4*)(proj + ((size_t)((unsigned)(rA * N + sA))) * DIM) + sub;
    const u32x4* hpA = (const u32x4*)(proj + ((size_t)((unsigned)(rA * N + dA))) * DIM) + sub;
    const u32x4* tpB = (const u32x4*)(proj + ((size_t)((unsigned)(rB * N + sB))) * DIM) + sub;
    const u32x4* hpB = (const u32x4*)(proj + ((size_t)((unsigned)(rB * N + dB))) * DIM) + sub;
    const f32x4* efA = (const f32x4*)(efeat + (size_t)eA * DIM) + sub * 2;
    const f32x4* efB = (const f32x4*)(efeat + (size_t)eBc * DIM) + sub * 2;

    // issue all 12 loads; compiler schedules them ahead of the math
    u32x4 tuA = *tpA;
    u32x4 huA = *hpA;
    u32x4 tuB = *tpB;
    u32x4 huB = *hpB;
    f32x4 efa0 = __builtin_nontemporal_load(efA);
    f32x4 efa1 = __builtin_nontemporal_load(efA + 1);
    f32x4 efb0 = __builtin_nontemporal_load(efB);
    f32x4 efb1 = __builtin_nontemporal_load(efB + 1);

    float tfA[8], hfA[8], tfB[8], hfB[8];
    bf8up(tuA, tfA);
    bf8up(huA, hfA);
    bf8up(tuB, tfB);
    bf8up(huB, hfB);
    float evA[8] = {efa0[0], efa0[1], efa0[2], efa0[3], efa1[0], efa1[1], efa1[2], efa1[3]};
    float evB[8] = {efb0[0], efb0[1], efb0[2], efb0[3], efb1[0], efb1[1], efb1[2], efb1[3]};

    float dotA = 0.f, dotB = 0.f;
#pragma unroll
    for (int i = 0; i < 8; ++i) {
        dotA = fmaf(tfA[i], fast_tanh(hfA[i] + evA[i]), dotA);
        dotB = fmaf(tfB[i], fast_tanh(hfB[i] + evB[i]), dotB);
    }

    // reduce both dots across the 8-lane group
    dotA += __shfl_xor(dotA, 1);
    dotA += __shfl_xor(dotA, 2);
    dotA += __shfl_xor(dotA, 4);
    dotB += __shfl_xor(dotB, 1);
    dotB += __shfl_xor(dotB, 2);
    dotB += __shfl_xor(dotB, 4);

    int pA = off[dA] + rank[eA];
    if (sub == 0) att_s[pA] = dotA;
    if (sub == 1) src_s[pA] = sA;
    if (hasB) {
        int pB = off[dB] + rank[eB];
        if (sub == 2) att_s[pB] = dotB;
        if (sub == 3) src_s[pB] = sB;
    }
}

// ---------------------------------------------------------------------------
// Pure softmax + aggregation. Wave per node, NO LDS.
// Quarter-wave float4 gathers: one VMEM instr covers 4 nfeat rows.
// ---------------------------------------------------------------------------
__global__ __launch_bounds__(256) void k_agg(const float* __restrict__ att_s,
                                             const int* __restrict__ src_s,
                                             const float* __restrict__ nfeat,
                                             const int* __restrict__ off,
                                             float* __restrict__ hn, int N) {
    const int node = blockIdx.x * 4 + (threadIdx.x >> 6);
    if (node >= N) return;
    const int lane = threadIdx.x & 63;
    const int qw = lane >> 4;   // quarter-wave index (row slot)
    const int ql = lane & 15;   // lane within quarter (4-dim slice)

    const int jb = off[node];
    const int je = off[node + 1];

    float m = -INFINITY;
    for (int j0 = jb; j0 < je; j0 += 64) {
        int j = j0 + lane;
        float a = (j < je) ? att_s[j] : -INFINITY;
        m = fmaxf(m, a);
    }
#pragma unroll
    for (int ms = 32; ms; ms >>= 1) m = fmaxf(m, __shfl_xor(m, ms));

    float pl = 0.f;
    f32x4 acc = {0.f, 0.f, 0.f, 0.f};
    for (int j0 = jb; j0 < je; j0 += 64) {
        int j = j0 + lane;
        int cnt = min(64, je - j0);
        float a = (j < je) ? att_s[j] : -INFINITY;
        float p = __expf(a - m);
        int s = (j < je) ? src_s[j] : 0;
        pl += p;

        int jj = 0;
        for (; jj + 15 < cnt; jj += 16) {
            float pj[4]; int sj[4]; f32x4 x[4];
#pragma unroll
            for (int u = 0; u < 4; ++u) {
                int eidx = jj + u * 4 + qw;
                pj[u] = __shfl(p, eidx);
                sj[u] = __shfl(s, eidx);
            }
#pragma unroll
            for (int u = 0; u < 4; ++u)
                x[u] = *(const f32x4*)&nfeat[(size_t)sj[u] * DIM + ql * 4];
#pragma unroll
            for (int u = 0; u < 4; ++u) {
                acc[0] = fmaf(pj[u], x[u][0], acc[0]);
                acc[1] = fmaf(pj[u], x[u][1], acc[1]);
                acc[2] = fmaf(pj[u], x[u][2], acc[2]);
                acc[3] = fmaf(pj[u], x[u][3], acc[3]);
            }
        }
        for (; jj < cnt; jj += 4) {
            int eidx = jj + qw;
            int ec = (eidx < cnt) ? eidx : (cnt - 1);
            float pj = __shfl(p, ec);
            int sj = __shfl(s, ec);
            if (eidx < cnt) {
                f32x4 x = *(const f32x4*)&nfeat[(size_t)sj * DIM + ql * 4];
                acc[0] = fmaf(pj, x[0], acc[0]);
                acc[1] = fmaf(pj, x[1], acc[1]);
                acc[2] = fmaf(pj, x[2], acc[2]);
                acc[3] = fmaf(pj, x[3], acc[3]);
            }
        }
    }
#pragma unroll
    for (int ms = 32; ms; ms >>= 1) pl += __shfl_xor(pl, ms);

#pragma unroll
    for (int c = 0; c < 4; ++c) {
        acc[c] += __shfl_xor(acc[c], 16);
        acc[c] += __shfl_xor(acc[c], 32);
    }

    const float inv = (je > jb) ? 1.0f / pl : 0.f;
    if (qw == 0) {
        f32x4 hv = {acc[0] * inv, acc[1] * inv, acc[2] * inv, acc[3] * inv};
        *(f32x4*)&hn[(size_t)node * DIM + ql * 4] = hv;
    }
}

// ---------------------------------------------------------------------------
// Bi-interaction: out = lrelu((nf+hn)@W1) + lrelu((nf*hn)@W2), MFMA f16.
// ---------------------------------------------------------------------------
__global__ __launch_bounds__(256) void k_bi(const float* __restrict__ nfeat,
                                            const float* __restrict__ hn,
                                            const float* __restrict__ W1,
                                            const float* __restrict__ W2,
                                            float* __restrict__ out, int N) {
    __shared__ _Float16 shMem[4 * 64 * PA];
    _Float16* shA1 = shMem;
    _Float16* shA2 = shMem + 64 * PA;
    _Float16* shB1 = shMem + 2 * 64 * PA;
    _Float16* shB2 = shMem + 3 * 64 * PA;

    const int tx = threadIdx.x;
    const int n0 = blockIdx.x * 64;

    const float4* nf4 = (const float4*)(nfeat + (size_t)n0 * DIM);
    const float4* hn4 = (const float4*)(hn + (size_t)n0 * DIM);
#pragma unroll
    for (int i = 0; i < 4; ++i) {
        int idx = tx + 256 * i;
        int row = idx >> 4, c = idx & 15;
        bool ok = (n0 + row < N);
        float4 a = ok ? nf4[idx] : f4zero();
        float4 b = ok ? hn4[idx] : f4zero();
        _Float16* p1 = &shA1[row * PA + c * 4];
        _Float16* p2 = &shA2[row * PA + c * 4];
        p1[0] = (_Float16)(a.x + b.x); p2[0] = (_Float16)(a.x * b.x);
        p1[1] = (_Float16)(a.y + b.y); p2[1] = (_Float16)(a.y * b.y);
        p1[2] = (_Float16)(a.z + b.z); p2[2] = (_Float16)(a.z * b.z);
        p1[3] = (_Float16)(a.w + b.w); p2[3] = (_Float16)(a.w * b.w);
    }
    const float4* w14 = (const float4*)W1;
    const float4* w24 = (const float4*)W2;
#pragma unroll
    for (int i = 0; i < 4; ++i) {
        int idx = tx + 256 * i;
        int k = idx >> 4, c = (idx & 15) * 4;
        float4 v = w14[idx];
        shB1[(c + 0) * PA + k] = (_Float16)v.x;
        shB1[(c + 1) * PA + k] = (_Float16)v.y;
        shB1[(c + 2) * PA + k] = (_Float16)v.z;
        shB1[(c + 3) * PA + k] = (_Float16)v.w;
        float4 u = w24[idx];
        shB2[(c + 0) * PA + k] = (_Float16)u.x;
        shB2[(c + 1) * PA + k] = (_Float16)u.y;
        shB2[(c + 2) * PA + k] = (_Float16)u.z;
        shB2[(c + 3) * PA + k] = (_Float16)u.w;
    }
    __syncthreads();

    const int w = tx >> 6;
    const int lane = tx & 63;
    const int lm = lane & 15;
    const int lq = lane >> 4;
    const int m0 = w * 16;

    half8 a10 = *(const half8*)&shA1[(m0 + lm) * PA + lq * 8];
    half8 a11 = *(const half8*)&shA1[(m0 + lm) * PA + 32 + lq * 8];
    half8 a20 = *(const half8*)&shA2[(m0 + lm) * PA + lq * 8];
    half8 a21 = *(const half8*)&shA2[(m0 + lm) * PA + 32 + lq * 8];

    f32x4 res[4];
#pragma unroll
    for (int ct = 0; ct < 4; ++ct) {
        half8 b10 = *(const half8*)&shB1[(ct * 16 + lm) * PA + lq * 8];
        half8 b11 = *(const half8*)&shB1[(ct * 16 + lm) * PA + 32 + lq * 8];
        half8 b20 = *(const half8*)&shB2[(ct * 16 + lm) * PA + lq * 8];
        half8 b21 = *(const half8*)&shB2[(ct * 16 + lm) * PA + 32 + lq * 8];
        f32x4 c1 = {0.f, 0.f, 0.f, 0.f};
        f32x4 c2 = {0.f, 0.f, 0.f, 0.f};
        c1 = __builtin_amdgcn_mfma_f32_16x16x32_f16(a10, b10, c1, 0, 0, 0);
        c1 = __builtin_amdgcn_mfma_f32_16x16x32_f16(a11, b11, c1, 0, 0, 0);
        c2 = __builtin_amdgcn_mfma_f32_16x16x32_f16(a20, b20, c2, 0, 0, 0);
        c2 = __builtin_amdgcn_mfma_f32_16x16x32_f16(a21, b21, c2, 0, 0, 0);
#pragma unroll
        for (int i = 0; i < 4; ++i) {
            float o1 = c1[i], o2 = c2[i];
            res[ct][i] = (o1 >= 0.f ? o1 : 0.01f * o1) + (o2 >= 0.f ? o2 : 0.01f * o2);
        }
    }

    __syncthreads();
    float* shSt = (float*)shMem;   // 64*68*4 = 17408B <= 36864B
#pragma unroll
    for (int ct = 0; ct < 4; ++ct)
#pragma unroll
        for (int i = 0; i < 4; ++i)
            shSt[(m0 + lq * 4 + i) * 68 + ct * 16 + lm] = res[ct][i];
    __syncthreads();

    float* outp = out + (size_t)n0 * DIM;
#pragma unroll
    for (int k = 0; k < 4; ++k) {
        int idx = tx + 256 * k;
        int row = idx >> 4, cc = idx & 15;
        if (n0 + row < N) {
            float4 v = *(const float4*)&shSt[row * 68 + cc * 4];
            *(float4*)&outp[(size_t)row * DIM + cc * 4] = v;
        }
    }
}

extern "C" void kernel_launch(void* const* d_in, const int* in_sizes, int n_in,
                              void* d_out, int out_size, void* d_ws, size_t ws_size,
                              hipStream_t stream) {
    const float* nfeat = (const float*)d_in[0];
    const float* efeat = (const float*)d_in[1];
    const float* relW  = (const float*)d_in[2];
    const float* W1    = (const float*)d_in[3];
    const float* W2    = (const float*)d_in[4];
    const int* src   = (const int*)d_in[5];
    const int* dst   = (const int*)d_in[6];
    const int* etype = (const int*)d_in[7];

    const int N = in_sizes[0] / DIM;
    const int E = in_sizes[5];
    const int R = in_sizes[2] / (DIM * DIM);
    const int NB = (N + 255) / 256;   // scan blocks (<=256)

    float* out = (float*)d_out;
    float* hn  = out;
    float* bi  = out + (size_t)N * DIM;

    // ws: proj bf16 | deg[N] | off[N+1] | epart[N] | bsum[256] | rank[E] | src_s[E] | att_s[E]
    unsigned short* proj = (unsigned short*)d_ws;
    size_t projElems = (size_t)R * N * DIM;
    int* deg    = (int*)(proj + projElems);
    int* off    = deg + N;
    int* epart  = off + (N + 1);
    int* bsum   = epart + N;
    int* rank   = bsum + 256;
    int* src_s  = rank + E;
    float* att_s = (float*)(src_s + E);

    (void)hipMemsetAsync(deg, 0, (size_t)N * sizeof(int), stream);

    k_hist<<<(E + 255) / 256, 256, 0, stream>>>(dst, deg, rank, E);
    k_scan1<<<NB, 256, 0, stream>>>(deg, epart, bsum, N);
    k_scan2<<<1, 1024, 0, stream>>>(epart, bsum, NB, off, N, E);

    dim3 gProj((N + 63) / 64, 4);
    k_proj<<<gProj, 256, 0, stream>>>(nfeat, relW, proj, N, R);

    // 8 threads per 2 edges -> E*4 threads total
    k_att<<<((size_t)E * 4 + 255) / 256, 256, 0, stream>>>(proj, efeat, src, dst, etype,
                                                           rank, off, att_s, src_s, N, E);

    k_agg<<<(N + 3) / 4, 256, 0, stream>>>(att_s, src_s, nfeat, off, hn, N);

    k_bi<<<(N + 63) / 64, 256, 0, stream>>>(nfeat, hn, W1, W2, bi, N);
}